// Round 2
// baseline (298.942 us; speedup 1.0000x reference)
//
#include <hip/hip_runtime.h>

// ---------------------------------------------------------------------------
// InversePerspectiveProjection: project D*H*W voxels into 6 images, bilinear
// sample 64 channels, mean over images.
//
// R2 structure (R1 + pragma placement fix):
//   k1 transpose: images (N,C,Hi,Wi) -> imgT (N,Hi*Wi,C)  [channel-contig]
//   k2 geometry : per (p,n) -> {4 weights (mask/valid/(1/6) folded), 4 offsets}
//   k3 sample   : lane=channel, 256B coalesced gathers, LDS transpose for
//                 coalesced (C,P) output writes.
// ---------------------------------------------------------------------------

#define N_IMG 6
#define C_CH  64
#define HI    224
#define WI    400
#define HW    (HI * WI)          // 89600
#define D_RES 8
#define H_RES 128
#define W_RES 128
#define P_TOT (D_RES * H_RES * W_RES)   // 131072
#define VOX   0.4f

struct Rec {                     // 32 B, one per (point, image)
    float w00, w10, w01, w11;    // bilinear weights * (1/6), 0 if invalid/masked
    int   o00, o10, o01, o11;    // element offsets into imgT (corner base, +lane for channel)
};

// ---------------- k1: transpose (N,C,HW) -> (N,HW,C) -----------------------
__global__ __launch_bounds__(256) void transpose_k(const float* __restrict__ in,
                                                   float* __restrict__ out) {
    __shared__ float tile[64 * 65];          // +1 pad: conflict-free both phases
    int b      = blockIdx.x;
    int n      = b / 1400;                    // HW/64 = 1400 tiles per image
    int s_base = (b % 1400) * 64;
    int t    = threadIdx.x;
    int lane = t & 63;
    int sub  = t >> 6;                        // 0..3

    const float* inp = in + (size_t)n * C_CH * HW;
#pragma unroll
    for (int i = 0; i < 16; ++i) {
        int c = sub + 4 * i;                  // wave-uniform channel
        tile[lane * 65 + c] = inp[(size_t)c * HW + s_base + lane];  // 256B coalesced read
    }
    __syncthreads();
    float* outp = out + ((size_t)n * HW + s_base) * C_CH;
#pragma unroll
    for (int i = 0; i < 16; ++i) {
        int s_local = sub + 4 * i;            // wave-uniform pixel
        outp[(size_t)s_local * C_CH + lane] = tile[s_local * 65 + lane]; // 256B coalesced write
    }
}

// ---------------- k2: per-(p,n) geometry -> Rec ----------------------------
__global__ __launch_bounds__(256) void geom_k(const float* __restrict__ Kmat,
                                              const float* __restrict__ Rmat,
                                              const float* __restrict__ Tvec,
                                              Rec* __restrict__ recs) {
#pragma clang fp contract(off)               // match numpy's non-fused rounding (mask boundary)
    int t = blockIdx.x * 256 + threadIdx.x;   // t = p*6 + n  (stores coalesced)
    int p = t / N_IMG;
    int n = t - p * N_IMG;

    // flat p is in meshgrid (H,W,D) order: p = ih*1024 + iw*8 + id
    int ih = p >> 10;
    int iw = (p >> 3) & (W_RES - 1);
    int id = p & (D_RES - 1);

    float px = ((float)ih - 63.5f) * VOX;
    float py = ((float)iw - 63.5f) * VOX;
    float pz = ((float)id - 3.5f) * VOX;

    const float* R = Rmat + n * 9;
    const float* K = Kmat + n * 9;
    const float* T = Tvec + n * 3;

    float cx = px * R[0] + py * R[1] + pz * R[2] + T[0];
    float cy = px * R[3] + py * R[4] + pz * R[5] + T[1];
    float cz = px * R[6] + py * R[7] + pz * R[8] + T[2];

    float pix0 = cx * K[0] + cy * K[1] + cz * K[2];
    float pix1 = cx * K[3] + cy * K[4] + cz * K[5];
    float pix2 = cx * K[6] + cy * K[7] + cz * K[8];

    Rec r;
    if (pix2 < 0.1f) {                        // masked: contributes exactly 0
        r.w00 = r.w10 = r.w01 = r.w11 = 0.0f;
        r.o00 = r.o10 = r.o01 = r.o11 = n * (HW * C_CH);
    } else {
        float u = pix0 / pix2;                // IEEE div, as reference
        float v = pix1 / pix2;
        // g = 2*uv[::-1]/scale - 1 ; xs from g0 (scale Hi-1), ys from g1 (scale Wi-1)
        float g0 = 2.0f * v / 223.0f - 1.0f;
        float g1 = 2.0f * u / 399.0f - 1.0f;
        float xs = ((g0 + 1.0f) * 400.0f - 1.0f) * 0.5f;
        float ys = ((g1 + 1.0f) * 224.0f - 1.0f) * 0.5f;
        xs = fminf(fmaxf(xs, -10.0f), 410.0f);
        ys = fminf(fmaxf(ys, -10.0f), 234.0f);
        float x0f = floorf(xs), y0f = floorf(ys);
        float wx = xs - x0f, wy = ys - y0f;
        int x0 = (int)x0f, y0 = (int)y0f;
        int x1 = x0 + 1, y1 = y0 + 1;
        bool vx0 = (x0 >= 0) & (x0 < WI);
        bool vx1 = (x1 >= 0) & (x1 < WI);
        bool vy0 = (y0 >= 0) & (y0 < HI);
        bool vy1 = (y1 >= 0) & (y1 < HI);
        float omwx = 1.0f - wx, omwy = 1.0f - wy;
        const float inv6 = 1.0f / 6.0f;
        r.w00 = (vx0 & vy0) ? omwx * omwy * inv6 : 0.0f;
        r.w10 = (vx1 & vy0) ? wx   * omwy * inv6 : 0.0f;
        r.w01 = (vx0 & vy1) ? omwx * wy   * inv6 : 0.0f;
        r.w11 = (vx1 & vy1) ? wx   * wy   * inv6 : 0.0f;
        int xc0 = min(max(x0, 0), WI - 1), xc1 = min(max(x1, 0), WI - 1);
        int yc0 = min(max(y0, 0), HI - 1), yc1 = min(max(y1, 0), HI - 1);
        int base = n * (HW * C_CH);
        r.o00 = base + (yc0 * WI + xc0) * C_CH;
        r.o10 = base + (yc0 * WI + xc1) * C_CH;
        r.o01 = base + (yc1 * WI + xc0) * C_CH;
        r.o11 = base + (yc1 * WI + xc1) * C_CH;
    }
    recs[t] = r;
}

// ---------------- k3: gather + accumulate + transpose-write ----------------
__global__ __launch_bounds__(256) void sample_k(const float* __restrict__ imgT,
                                                const Rec* __restrict__ recs,
                                                float* __restrict__ out) {
    __shared__ float4 sbuf[768];              // 64 points * 6 recs * 32 B = 12 KB
    __shared__ float  sout[64 * 65];          // acc tile, padded

    int t      = threadIdx.x;
    int p_base = blockIdx.x * 64;

    // preload this block's records (contiguous: recs[p*6+n]) — coalesced
    const float4* grec = (const float4*)(recs + (size_t)p_base * N_IMG);
#pragma unroll
    for (int j = 0; j < 3; ++j) sbuf[t + 256 * j] = grec[t + 256 * j];
    __syncthreads();

    const Rec* sr = (const Rec*)sbuf;
    int lane = t & 63;                        // = channel
    int w    = t >> 6;                        // wave id 0..3

    for (int lp = 0; lp < 16; ++lp) {
        int pl = w * 16 + lp;                 // block-local point
        float acc = 0.0f;
#pragma unroll
        for (int n = 0; n < N_IMG; ++n) {
            Rec r = sr[pl * N_IMG + n];       // LDS broadcast (wave-uniform)
            float v00 = imgT[r.o00 + lane];   // 256 B aligned coalesced gathers
            float v10 = imgT[r.o10 + lane];
            float v01 = imgT[r.o01 + lane];
            float v11 = imgT[r.o11 + lane];
            acc = fmaf(r.w00, v00, acc);
            acc = fmaf(r.w10, v10, acc);
            acc = fmaf(r.w01, v01, acc);
            acc = fmaf(r.w11, v11, acc);
        }
        sout[pl * 65 + lane] = acc;
    }
    __syncthreads();

    // write out[c*P + p]: lane = point, wave-uniform channel -> 256 B stores
    int csub = t >> 6;
#pragma unroll
    for (int i = 0; i < 16; ++i) {
        int c = csub * 16 + i;
        out[(size_t)c * P_TOT + p_base + lane] = sout[lane * 65 + c];
    }
}

// ---------------------------------------------------------------------------
extern "C" void kernel_launch(void* const* d_in, const int* in_sizes, int n_in,
                              void* d_out, int out_size, void* d_ws, size_t ws_size,
                              hipStream_t stream) {
    const float* images = (const float*)d_in[0];
    const float* intr   = (const float*)d_in[1];
    const float* rot    = (const float*)d_in[2];
    const float* trans  = (const float*)d_in[3];
    // d_in[4..7] = D,H,W,voxelsize — compile-time constants here.

    float* imgT = (float*)d_ws;                                   // 137.6 MB
    Rec*   recs = (Rec*)((char*)d_ws + (size_t)N_IMG * HW * C_CH * 4); // +25.2 MB
    float* outp = (float*)d_out;

    transpose_k<<<N_IMG * (HW / 64), 256, 0, stream>>>(images, imgT);
    geom_k<<<(P_TOT * N_IMG) / 256, 256, 0, stream>>>(intr, rot, trans, recs);
    sample_k<<<P_TOT / 64, 256, 0, stream>>>(imgT, recs, outp);
}

// Round 5
// 287.391 us; speedup vs baseline: 1.0402x; 1.0402x over previous
//
#include <hip/hip_runtime.h>
#include <hip/hip_fp16.h>

// ---------------------------------------------------------------------------
// InversePerspectiveProjection. R5 = R4 + fix: geometry phase now covers all
// 384 recs with a strided loop (R3/R4 used `if (t < 384)` in a 256-thread
// block -> recs 256..383 were uninitialized LDS -> wild gathers -> GPU fault).
//   k1 transpose: images (N,C,Hi,Wi) fp32 -> imgT (N,Hi*Wi,C) fp16
//   k2 fused    : per-block geometry (384 recs -> LDS as float4+int4) +
//                 half2 gather (half-wave = one pixel's 128 B channel block),
//                 LDS transpose -> coalesced (C,P) fp32 output stores.
// ---------------------------------------------------------------------------

#define N_IMG 6
#define C_CH  64
#define HI    224
#define WI    400
#define HW    (HI * WI)          // 89600
#define D_RES 8
#define H_RES 128
#define W_RES 128
#define P_TOT (D_RES * H_RES * W_RES)   // 131072
#define VOX   0.4f

// ---------------- k1: transpose+convert (N,C,HW) fp32 -> (N,HW,C) fp16 -----
__global__ __launch_bounds__(256) void transpose_k(const float* __restrict__ in,
                                                   __half* __restrict__ outh) {
    __shared__ float tile[64 * 65];          // [c][pix], row pitch 65
    int b      = blockIdx.x;
    int n      = b / 1400;                    // HW/64 = 1400 tiles per image
    int s_base = (b % 1400) * 64;
    int t    = threadIdx.x;
    int col4 = t & 15;                        // pixel quad within tile
    int crow = t >> 4;                        // 0..15

    const float* inp = in + (size_t)n * C_CH * HW + s_base;
#pragma unroll
    for (int i = 0; i < 4; ++i) {
        int c = i * 16 + crow;
        const float4 v = *(const float4*)(inp + (size_t)c * HW + 4 * col4); // 16B aligned
        tile[c * 65 + 4 * col4 + 0] = v.x;
        tile[c * 65 + 4 * col4 + 1] = v.y;
        tile[c * 65 + 4 * col4 + 2] = v.z;
        tile[c * 65 + 4 * col4 + 3] = v.w;
    }
    __syncthreads();

    // write: per pixel 64ch * 2B = 128 B; thread covers 4 ch = one 8 B store
    struct H4 { __half2 a, b; };              // 8 B
    int ch4 = 4 * (t & 15);
    H4* outp = (H4*)outh;
#pragma unroll
    for (int i = 0; i < 4; ++i) {
        int pix = i * 16 + (t >> 4);
        H4 pk;
        pk.a = __floats2half2_rn(tile[(ch4 + 0) * 65 + pix],
                                 tile[(ch4 + 1) * 65 + pix]);
        pk.b = __floats2half2_rn(tile[(ch4 + 2) * 65 + pix],
                                 tile[(ch4 + 3) * 65 + pix]);
        outp[(size_t)(n * HW + s_base + pix) * 16 + (ch4 >> 2)] = pk;
    }
}

// ---------------- geometry for one (point, image) --------------------------
// weights carry mask/validity/(1/6); offsets are half2-unit pixel-block bases.
__device__ __forceinline__ void make_rec(int p, int n,
                                         const float* __restrict__ Kmat,
                                         const float* __restrict__ Rmat,
                                         const float* __restrict__ Tvec,
                                         float4& wout, int4& oout) {
#pragma clang fp contract(off)               // match numpy rounding (mask boundary)
    // flat p is meshgrid (H,W,D) order: p = ih*1024 + iw*8 + id
    int ih = p >> 10;
    int iw = (p >> 3) & (W_RES - 1);
    int id = p & (D_RES - 1);

    float px = ((float)ih - 63.5f) * VOX;
    float py = ((float)iw - 63.5f) * VOX;
    float pz = ((float)id - 3.5f) * VOX;

    const float* R = Rmat + n * 9;
    const float* K = Kmat + n * 9;
    const float* T = Tvec + n * 3;

    float cx = px * R[0] + py * R[1] + pz * R[2] + T[0];
    float cy = px * R[3] + py * R[4] + pz * R[5] + T[1];
    float cz = px * R[6] + py * R[7] + pz * R[8] + T[2];

    float pix0 = cx * K[0] + cy * K[1] + cz * K[2];
    float pix1 = cx * K[3] + cy * K[4] + cz * K[5];
    float pix2 = cx * K[6] + cy * K[7] + cz * K[8];

    if (pix2 < 0.1f) {
        wout = make_float4(0.0f, 0.0f, 0.0f, 0.0f);
        int b = n * (HW * 32);
        oout = make_int4(b, b, b, b);
        return;
    }
    float u = pix0 / pix2;
    float v = pix1 / pix2;
    float g0 = 2.0f * v / 223.0f - 1.0f;
    float g1 = 2.0f * u / 399.0f - 1.0f;
    float xs = ((g0 + 1.0f) * 400.0f - 1.0f) * 0.5f;
    float ys = ((g1 + 1.0f) * 224.0f - 1.0f) * 0.5f;
    xs = fminf(fmaxf(xs, -10.0f), 410.0f);
    ys = fminf(fmaxf(ys, -10.0f), 234.0f);
    float x0f = floorf(xs), y0f = floorf(ys);
    float wx = xs - x0f, wy = ys - y0f;
    int x0 = (int)x0f, y0 = (int)y0f;
    int x1 = x0 + 1, y1 = y0 + 1;
    bool vx0 = (x0 >= 0) & (x0 < WI);
    bool vx1 = (x1 >= 0) & (x1 < WI);
    bool vy0 = (y0 >= 0) & (y0 < HI);
    bool vy1 = (y1 >= 0) & (y1 < HI);
    float omwx = 1.0f - wx, omwy = 1.0f - wy;
    const float inv6 = 1.0f / 6.0f;
    wout.x = (vx0 & vy0) ? omwx * omwy * inv6 : 0.0f;
    wout.y = (vx1 & vy0) ? wx   * omwy * inv6 : 0.0f;
    wout.z = (vx0 & vy1) ? omwx * wy   * inv6 : 0.0f;
    wout.w = (vx1 & vy1) ? wx   * wy   * inv6 : 0.0f;
    int xc0 = min(max(x0, 0), WI - 1), xc1 = min(max(x1, 0), WI - 1);
    int yc0 = min(max(y0, 0), HI - 1), yc1 = min(max(y1, 0), HI - 1);
    int base = n * (HW * 32);                 // half2 units: 32 per pixel
    oout.x = base + (yc0 * WI + xc0) * 32;
    oout.y = base + (yc0 * WI + xc1) * 32;
    oout.z = base + (yc1 * WI + xc0) * 32;
    oout.w = base + (yc1 * WI + xc1) * 32;
}

// ---------------- k2: fused geometry + gather + transpose-write ------------
__global__ __launch_bounds__(256) void sample_k(const float* __restrict__ Kmat,
                                                const float* __restrict__ Rmat,
                                                const float* __restrict__ Tvec,
                                                const __half2* __restrict__ imgT2,
                                                float* __restrict__ out) {
    __shared__ float4 swt[64 * N_IMG];        // 6 KB weights
    __shared__ int4   sof[64 * N_IMG];        // 6 KB offsets
    __shared__ float  sout[64 * 66];          // 16.9 KB acc tile

    int t      = threadIdx.x;
    int p_base = blockIdx.x * 64;

    // ALL 384 recs, strided over the 256 threads (R3/R4 bug: if(t<384) left
    // recs 256..383 as uninitialized LDS -> wild gather addresses -> fault)
    for (int i = t; i < 64 * N_IMG; i += 256) {
        float4 w; int4 o;
        make_rec(p_base + i / N_IMG, i % N_IMG, Kmat, Rmat, Tvec, w, o);
        swt[i] = w;
        sof[i] = o;
    }
    __syncthreads();

    // gather: half-wave = 32 lanes x half2 = one pixel's 128 B channel block
    int lane = t & 63;
    int wv   = t >> 6;                        // wave 0..3 -> points wv*16..+15
    int l    = lane & 31;                     // half2 channel pair
    int q    = lane >> 5;                     // which of 2 points this pass

    for (int j = 0; j < 8; ++j) {             // rolled: keeps VGPRs modest
        int pl = wv * 16 + j * 2 + q;         // block-local point
        float accx = 0.0f, accy = 0.0f;
#pragma unroll
        for (int n = 0; n < N_IMG; ++n) {
            float4 wt = swt[pl * N_IMG + n];  // ds_read_b128
            int4   of = sof[pl * N_IMG + n];  // ds_read_b128
            float2 f00 = __half22float2(imgT2[of.x + l]);
            float2 f10 = __half22float2(imgT2[of.y + l]);
            float2 f01 = __half22float2(imgT2[of.z + l]);
            float2 f11 = __half22float2(imgT2[of.w + l]);
            accx = fmaf(wt.x, f00.x, accx);  accy = fmaf(wt.x, f00.y, accy);
            accx = fmaf(wt.y, f10.x, accx);  accy = fmaf(wt.y, f10.y, accy);
            accx = fmaf(wt.z, f01.x, accx);  accy = fmaf(wt.z, f01.y, accy);
            accx = fmaf(wt.w, f11.x, accx);  accy = fmaf(wt.w, f11.y, accy);
        }
        sout[pl * 66 + 2 * l + 0] = accx;
        sout[pl * 66 + 2 * l + 1] = accy;
    }
    __syncthreads();

    // output: out[c*P + p], lane = point -> 256 B coalesced stores
    int csub = t >> 6;
#pragma unroll
    for (int i = 0; i < 16; ++i) {
        int c = csub * 16 + i;
        out[(size_t)c * P_TOT + p_base + lane] = sout[lane * 66 + c];
    }
}

// ---------------------------------------------------------------------------
extern "C" void kernel_launch(void* const* d_in, const int* in_sizes, int n_in,
                              void* d_out, int out_size, void* d_ws, size_t ws_size,
                              hipStream_t stream) {
    const float* images = (const float*)d_in[0];
    const float* intr   = (const float*)d_in[1];
    const float* rot    = (const float*)d_in[2];
    const float* trans  = (const float*)d_in[3];

    __half* imgT = (__half*)d_ws;             // 6*89600*64*2 B = 68.8 MB
    float*  outp = (float*)d_out;

    transpose_k<<<N_IMG * (HW / 64), 256, 0, stream>>>(images, imgT);
    sample_k<<<P_TOT / 64, 256, 0, stream>>>(intr, rot, trans,
                                             (const __half2*)imgT, outp);
}

// Round 6
// 257.585 us; speedup vs baseline: 1.1606x; 1.1157x over previous
//
#include <hip/hip_runtime.h>
#include <hip/hip_fp16.h>

// ---------------------------------------------------------------------------
// InversePerspectiveProjection. R6:
//   k1 transpose: images (N,C,Hi,Wi) fp32 -> imgT (N,Hi*Wi,C) fp16
//   k2 fused    : geometry emits per-(point,cam) {4 remapped weights, 1 row
//                 base}; gather = 2 contiguous 256 B wave-loads per (pt,cam)
//                 (row pair), cross-half shfl reduce, LDS transpose ->
//                 coalesced (C,P) fp32 stores. XCD-aware block swizzle.
// ---------------------------------------------------------------------------

#define N_IMG 6
#define C_CH  64
#define HI    224
#define WI    400
#define HW    (HI * WI)          // 89600
#define D_RES 8
#define H_RES 128
#define W_RES 128
#define P_TOT (D_RES * H_RES * W_RES)   // 131072
#define VOX   0.4f
#define ROWH2 (WI * 32)          // half2 units per image row (12800)

// ---------------- k1: transpose+convert (N,C,HW) fp32 -> (N,HW,C) fp16 -----
__global__ __launch_bounds__(256) void transpose_k(const float* __restrict__ in,
                                                   __half* __restrict__ outh) {
    __shared__ float tile[64 * 65];          // [c][pix], row pitch 65
    int b      = blockIdx.x;
    int n      = b / 1400;                    // HW/64 = 1400 tiles per image
    int s_base = (b % 1400) * 64;
    int t    = threadIdx.x;
    int col4 = t & 15;                        // pixel quad within tile
    int crow = t >> 4;                        // 0..15

    const float* inp = in + (size_t)n * C_CH * HW + s_base;
#pragma unroll
    for (int i = 0; i < 4; ++i) {
        int c = i * 16 + crow;
        const float4 v = *(const float4*)(inp + (size_t)c * HW + 4 * col4); // 16B aligned
        tile[c * 65 + 4 * col4 + 0] = v.x;
        tile[c * 65 + 4 * col4 + 1] = v.y;
        tile[c * 65 + 4 * col4 + 2] = v.z;
        tile[c * 65 + 4 * col4 + 3] = v.w;
    }
    __syncthreads();

    // write: per pixel 64ch * 2B = 128 B; thread covers 4 ch = one 8 B store
    struct __align__(8) H4 { __half2 a, b; };
    int ch4 = 4 * (t & 15);
    H4* outp = (H4*)outh;
#pragma unroll
    for (int i = 0; i < 4; ++i) {
        int pix = i * 16 + (t >> 4);
        H4 pk;
        pk.a = __floats2half2_rn(tile[(ch4 + 0) * 65 + pix],
                                 tile[(ch4 + 1) * 65 + pix]);
        pk.b = __floats2half2_rn(tile[(ch4 + 2) * 65 + pix],
                                 tile[(ch4 + 3) * 65 + pix]);
        outp[(size_t)(n * HW + s_base + pix) * 16 + (ch4 >> 2)] = pk;
    }
}

// ---------------- geometry for one (point, image) --------------------------
// Emits weights remapped onto the clamped 2x2 block at (by..by+1, bx..bx+1):
//   wout = inv6 * (wxA*wyA, wxB*wyA, wxA*wyB, wxB*wyB), zeros for invalid/mask
//   oout = half2-unit offset of (by, bx) pixel block.
__device__ __forceinline__ void make_rec(int p, int n,
                                         const float* __restrict__ Kmat,
                                         const float* __restrict__ Rmat,
                                         const float* __restrict__ Tvec,
                                         float4& wout, int& oout) {
#pragma clang fp contract(off)               // match numpy rounding (mask boundary)
    // flat p is meshgrid (H,W,D) order: p = ih*1024 + iw*8 + id
    int ih = p >> 10;
    int iw = (p >> 3) & (W_RES - 1);
    int id = p & (D_RES - 1);

    float px = ((float)ih - 63.5f) * VOX;
    float py = ((float)iw - 63.5f) * VOX;
    float pz = ((float)id - 3.5f) * VOX;

    const float* R = Rmat + n * 9;
    const float* K = Kmat + n * 9;
    const float* T = Tvec + n * 3;

    float cx = px * R[0] + py * R[1] + pz * R[2] + T[0];
    float cy = px * R[3] + py * R[4] + pz * R[5] + T[1];
    float cz = px * R[6] + py * R[7] + pz * R[8] + T[2];

    float pix0 = cx * K[0] + cy * K[1] + cz * K[2];
    float pix1 = cx * K[3] + cy * K[4] + cz * K[5];
    float pix2 = cx * K[6] + cy * K[7] + cz * K[8];

    if (pix2 < 0.1f) {
        wout = make_float4(0.0f, 0.0f, 0.0f, 0.0f);
        oout = n * (HW * 32);
        return;
    }
    float u = pix0 / pix2;
    float v = pix1 / pix2;
    float g0 = 2.0f * v / 223.0f - 1.0f;
    float g1 = 2.0f * u / 399.0f - 1.0f;
    float xs = ((g0 + 1.0f) * 400.0f - 1.0f) * 0.5f;
    float ys = ((g1 + 1.0f) * 224.0f - 1.0f) * 0.5f;
    xs = fminf(fmaxf(xs, -10.0f), 410.0f);
    ys = fminf(fmaxf(ys, -10.0f), 234.0f);
    float x0f = floorf(xs), y0f = floorf(ys);
    float wx = xs - x0f, wy = ys - y0f;
    int x0 = (int)x0f, y0 = (int)y0f;
    int x1 = x0 + 1, y1 = y0 + 1;

    int bx = min(max(x0, 0), WI - 2);
    int by = min(max(y0, 0), HI - 2);
    // weight of pixel q: (q==x0 ? 1-wx : q==x1 ? wx : 0) — folds validity+clamp
    float wxA = (bx     == x0) ? (1.0f - wx) : ((bx     == x1) ? wx : 0.0f);
    float wxB = (bx + 1 == x0) ? (1.0f - wx) : ((bx + 1 == x1) ? wx : 0.0f);
    float wyA = (by     == y0) ? (1.0f - wy) : ((by     == y1) ? wy : 0.0f);
    float wyB = (by + 1 == y0) ? (1.0f - wy) : ((by + 1 == y1) ? wy : 0.0f);

    const float inv6 = 1.0f / 6.0f;
    wout.x = wxA * wyA * inv6;                // row by  , pixel bx
    wout.y = wxB * wyA * inv6;                // row by  , pixel bx+1
    wout.z = wxA * wyB * inv6;                // row by+1, pixel bx
    wout.w = wxB * wyB * inv6;                // row by+1, pixel bx+1
    oout = n * (HW * 32) + (by * WI + bx) * 32;
}

// ---------------- k2: fused geometry + gather + transpose-write ------------
__global__ __launch_bounds__(256) void sample_k(const float* __restrict__ Kmat,
                                                const float* __restrict__ Rmat,
                                                const float* __restrict__ Tvec,
                                                const __half2* __restrict__ imgT2,
                                                float* __restrict__ out) {
    __shared__ float4 swt[64 * N_IMG];        // 6 KB weights
    __shared__ int    sof[64 * N_IMG];        // 1.5 KB row-base offsets
    __shared__ float  sout[64 * 66];          // 16.9 KB acc tile

    int t = threadIdx.x;
    // XCD-aware swizzle: each XCD gets a contiguous ih-slab (L2 locality)
    int bid    = ((blockIdx.x & 7) << 8) | (blockIdx.x >> 3);   // 2048 = 8*256
    int p_base = bid * 64;

    for (int i = t; i < 64 * N_IMG; i += 256) {
        float4 w; int o;
        make_rec(p_base + i / N_IMG, i % N_IMG, Kmat, Rmat, Tvec, w, o);
        swt[i] = w;
        sof[i] = o;
    }
    __syncthreads();

    // gather: one point per FULL wave; a row pair = 2 contiguous 256 B loads.
    // lane = (pixel half)*32 + channel-pair: imgT2[o + lane] covers bx,bx+1.
    int lane = t & 63;
    int wv   = t >> 6;                        // wave 0..3 -> points wv*16..+15
    int hi   = lane >> 5;                     // 0: pixel bx, 1: pixel bx+1

#pragma unroll 4
    for (int j = 0; j < 16; ++j) {
        int pl = wv * 16 + j;                 // block-local point
        float accx = 0.0f, accy = 0.0f;
#pragma unroll
        for (int n = 0; n < N_IMG; ++n) {
            float4 wt = swt[pl * N_IMG + n];  // broadcast ds_read_b128
            int    o  = sof[pl * N_IMG + n];
            float2 r0 = __half22float2(imgT2[o + lane]);          // row by
            float2 r1 = __half22float2(imgT2[o + ROWH2 + lane]);  // row by+1
            float w0 = hi ? wt.y : wt.x;
            float w1 = hi ? wt.w : wt.z;
            accx = fmaf(w0, r0.x, accx);  accy = fmaf(w0, r0.y, accy);
            accx = fmaf(w1, r1.x, accx);  accy = fmaf(w1, r1.y, accy);
        }
        accx += __shfl_xor(accx, 32, 64);     // combine the two pixel halves
        accy += __shfl_xor(accy, 32, 64);
        if (hi == 0)
            *(float2*)&sout[pl * 66 + 2 * (lane & 31)] = make_float2(accx, accy);
    }
    __syncthreads();

    // output: out[c*P + p], lane = point -> 256 B coalesced stores
    int csub = t >> 6;
#pragma unroll
    for (int i = 0; i < 16; ++i) {
        int c = csub * 16 + i;
        out[(size_t)c * P_TOT + p_base + lane] = sout[lane * 66 + c];
    }
}

// ---------------------------------------------------------------------------
extern "C" void kernel_launch(void* const* d_in, const int* in_sizes, int n_in,
                              void* d_out, int out_size, void* d_ws, size_t ws_size,
                              hipStream_t stream) {
    const float* images = (const float*)d_in[0];
    const float* intr   = (const float*)d_in[1];
    const float* rot    = (const float*)d_in[2];
    const float* trans  = (const float*)d_in[3];

    __half* imgT = (__half*)d_ws;             // 6*89600*64*2 B = 68.8 MB
    float*  outp = (float*)d_out;

    transpose_k<<<N_IMG * (HW / 64), 256, 0, stream>>>(images, imgT);
    sample_k<<<P_TOT / 64, 256, 0, stream>>>(intr, rot, trans,
                                             (const __half2*)imgT, outp);
}